// Round 8
// baseline (217.211 us; speedup 1.0000x reference)
//
#include <hip/hip_runtime.h>

// CommNet forward, fp32. B=512, M=32, H=256, NAG=8, NACT=16.
// R16: single fused kernel, zero cross-block deps. Each block (m, ct_o)
// computes the FULL hid[256][<=32ex] prelude itself (8x redundant across the
// 8 ct_o siblings; ~1 GFLOP total = cheap on VALU) then streams its 256-col
// Wo slice. Kills: k_linh launch + gap + hid global round-trip. Grid
// (32 m, 8 ct_o) = 256 blocks x 512 thr; 139.4 KB LDS -> 1 block/CU; m-major
// so ct_o siblings share an XCD (Wc/Wr 7/8 L2-served). All three 16-tile
// streams (Wc, Wr, Wo) use R15's proven depth-3 counted-vmcnt dual-barrier
// template (2 chunks/tile/wave; vmcnt 6/4/2/0; issue t+4 after trailing
// barrier; sched_barrier(0) pins). x staged in K-halves reusing one buffer.
// ct_o==0 blocks also write hid (coalesced from xs2) + softmax/baseline
// (8 waves x 4 slots), overlapped with the Wo prologue DMA.
// Kept: deterministic ballot grouping (R14); DMA dest = wave-uniform base +
// lane*16B, 256-float chunks (R5); no cooperative launch (R10); no acc8
// (R12); conservative vmcnt ledger under stray newer ops (R15).

constexpr int Bn = 512, Mn = 32, NAGn = 8, Hn = 256, NACTn = 16;
constexpr int On = Hn * NAGn;  // 2048
constexpr int En = 32;         // padded slots/model (counts <= 32: held R1-R15)
constexpr int XSa = 36;        // x LDS stride: 36*4=144B, %16==0 -> b128-aligned

__device__ __forceinline__ void gl_lds16(const float* g, float* l) {
  __builtin_amdgcn_global_load_lds(
      (const __attribute__((address_space(1))) void*)g,
      (__attribute__((address_space(3))) void*)l, 16, 0, 0);
}

// Deterministic per-model example list (512-thread version): slot j = j-th
// example (by index) with ids[e]==m. Identical in every block.
__device__ __forceinline__ int build_group_det(const int* __restrict__ ids,
                                               int m, int* lst, int* segc,
                                               int tid) {
  int w = tid >> 6, lane = tid & 63;
  if (tid < En) lst[tid] = -1;
  unsigned long long msk = __ballot(ids[tid] == m);  // 512 thr covers B=512
  if (lane == 0) segc[w] = __popcll(msk);
  __syncthreads();
  int tot = 0;
#pragma unroll
  for (int q = 0; q < 8; q++) tot += segc[q];
  int pre = 0;
#pragma unroll
  for (int q = 0; q < 8; q++)
    if (q < w) pre += segc[q];
  if ((msk >> lane) & 1ull) {
    int rank = pre + __popcll(msk & ((1ull << lane) - 1ull));
    if (rank < En) lst[rank] = tid;
  }
  __syncthreads();
  return tot;
}

// ---- fused kernel: grid (32 m, 8 ct_o) x 512 thr; 139.4 KB LDS, 1/CU ------
__global__ __launch_bounds__(512) void k_fused(
    const float* __restrict__ Wc, const float* __restrict__ Wr,
    const float* __restrict__ Wo, const float* __restrict__ comm_in,
    const float* __restrict__ prev_hid, const int* __restrict__ ids,
    const int* __restrict__ inp, const float* __restrict__ lut,
    const float* __restrict__ enc_bias, const float* __restrict__ bc,
    const float* __restrict__ br, const float* __restrict__ bo,
    const float* __restrict__ Wa, const float* __restrict__ ba,
    const float* __restrict__ Wb, const float* __restrict__ bb,
    float* __restrict__ hid, float* __restrict__ aprob,
    float* __restrict__ bl, float* __restrict__ comm_out) {
  int m = blockIdx.x, ct = blockIdx.y;  // ct = Wo col-slice 0..7 (256 cols)
  int tid = threadIdx.x, w = tid >> 6, lane = tid & 63;
  __shared__ int lst[En];
  __shared__ int segc[8];
  __shared__ alignas(16) float xs1[256 * XSa];     // 36.9 KB: x K-half
  __shared__ alignas(16) float xs2[256 * XSa];     // 36.9 KB: hid staging
  __shared__ alignas(16) float wbuf[4][16 * 256];  // 64 KB: stream tiles

  int cnt = build_group_det(ids, m, lst, segc, tid);
  if (cnt == 0) return;

  // tile issue: 16 rows x 256 cols; 8 waves x 2 rows; one 256-float row/chunk
  auto issue_tile = [&](const float* base, size_t rstride, int t) {
#pragma unroll
    for (int q = 0; q < 2; q++) {
      int r = w * 2 + q;
      gl_lds16(base + (size_t)(t * 16 + r) * rstride + lane * 4,
               wbuf[t & 3] + r * 256);
    }
  };

  int cp = 2 * (lane & 15);  // col-pair within wave's 32 cols
  int jo = (lane >> 4) * 8;  // ex octet base (4 octets x 8 = 32 ex)
  auto comp_tile = [&](const float* xsrc, int t, float2* acc) {
    const float* wb = wbuf[t & 3] + w * 32 + cp;
    const float* xb = xsrc + (size_t)(t * 16) * XSa + jo;
#pragma unroll 8
    for (int k = 0; k < 16; k++) {
      float2 wv = *(const float2*)(wb + k * 256);
      float4 xa = *(const float4*)(xb + k * XSa);
      float4 xc = *(const float4*)(xb + k * XSa + 4);
      acc[0].x += xa.x * wv.x; acc[0].y += xa.x * wv.y;
      acc[1].x += xa.y * wv.x; acc[1].y += xa.y * wv.y;
      acc[2].x += xa.z * wv.x; acc[2].y += xa.z * wv.y;
      acc[3].x += xa.w * wv.x; acc[3].y += xa.w * wv.y;
      acc[4].x += xc.x * wv.x; acc[4].y += xc.x * wv.y;
      acc[5].x += xc.y * wv.x; acc[5].y += xc.y * wv.y;
      acc[6].x += xc.z * wv.x; acc[6].y += xc.z * wv.y;
      acc[7].x += xc.w * wv.x; acc[7].y += xc.w * wv.y;
    }
  };

  // 16-tile stream, depth-3, counted vmcnt (R15-proven; waits are upper
  // bounds -> correct whether or not the ledger was drained or has newer
  // stray ops: tile t's chunks are always the oldest outstanding).
  auto stream16 = [&](const float* base, size_t rstride, const float* xsrc,
                      float2* acc) {
    for (int t = 0; t < 16; t++) {
      if (t <= 12)
        asm volatile("s_waitcnt vmcnt(6)" ::: "memory");
      else if (t == 13)
        asm volatile("s_waitcnt vmcnt(4)" ::: "memory");
      else if (t == 14)
        asm volatile("s_waitcnt vmcnt(2)" ::: "memory");
      else
        asm volatile("s_waitcnt vmcnt(0)" ::: "memory");
      __builtin_amdgcn_s_barrier();
      __builtin_amdgcn_sched_barrier(0);  // pin: no LDS read hoists above
      comp_tile(xsrc, t, acc);
      __builtin_amdgcn_sched_barrier(0);  // pin: no read sinks below
      __builtin_amdgcn_s_barrier();
      __builtin_amdgcn_sched_barrier(0);  // pin: restage/issue stays below
      if (t <= 11) issue_tile(base, rstride, t + 4);
    }
  };

  // ================= phase A: hid prelude (full 256 cols) ==================
  const float* WcB = Wc + (size_t)m * Hn * Hn;
  const float* WrB = Wr + (size_t)m * Hn * Hn;
#pragma unroll
  for (int t = 0; t < 4; t++) issue_tile(WcB, Hn, t);

  // stage comm half: xs1 row k = sum_a comm_in[e][a][k], k 0..255.
  // thread (kq=tid>>3, jg=tid&7): quad-rows kq*4.., ex j = jg*4+jx.
  // loads coalesce to 128B runs per ex; stores ~8-way bank alias (cheap).
  {
    int kq = tid >> 3, jg = tid & 7;
#pragma unroll
    for (int jx = 0; jx < 4; jx++) {
      int j = jg * 4 + jx;
      int e = lst[j];
      float4 vc = make_float4(0.f, 0.f, 0.f, 0.f);
      if (e >= 0) {
        const float4* cpp =
            (const float4*)(comm_in + (size_t)e * (NAGn * Hn)) + kq;
#pragma unroll
        for (int a = 0; a < NAGn; a++) {
          float4 tv = cpp[a * (Hn / 4)];
          vc.x += tv.x; vc.y += tv.y; vc.z += tv.z; vc.w += tv.w;
        }
      }
      int r = kq * 4;
      xs1[(r + 0) * XSa + j] = vc.x;
      xs1[(r + 1) * XSa + j] = vc.y;
      xs1[(r + 2) * XSa + j] = vc.z;
      xs1[(r + 3) * XSa + j] = vc.w;
    }
  }
  __syncthreads();  // full drain: Wc tiles 0..3 landed + xs1 visible

  float2 acc[8];
#pragma unroll
  for (int i = 0; i < 8; i++) acc[i] = make_float2(0.f, 0.f);
  stream16(WcB, Hn, xs1, acc);  // K 0..255 (comm @ Wc)

  // restage ph half into xs1 (safe: t=15 trailing barrier + sched pin ended
  // all xs1 reads). Issue Wr prologue first so DMA overlaps the restage.
#pragma unroll
  for (int t = 0; t < 4; t++) issue_tile(WrB, Hn, t);
  {
    int kq = tid >> 3, jg = tid & 7;
#pragma unroll
    for (int jx = 0; jx < 4; jx++) {
      int j = jg * 4 + jx;
      int e = lst[j];
      float4 vr = make_float4(0.f, 0.f, 0.f, 0.f);
      if (e >= 0) vr = *((const float4*)(prev_hid + (size_t)e * Hn) + kq);
      int r = kq * 4;
      xs1[(r + 0) * XSa + j] = vr.x;
      xs1[(r + 1) * XSa + j] = vr.y;
      xs1[(r + 2) * XSa + j] = vr.z;
      xs1[(r + 3) * XSa + j] = vr.w;
    }
  }
  __syncthreads();  // full drain: Wr tiles 0..3 + xs1 (ph) visible
  stream16(WrB, Hn, xs1, acc);  // K 256..511 (prev_hid @ Wr)

  // epilogue A: biases + tanh -> xs2[col][ex]
  int c0 = w * 32 + cp;  // this lane's col pair (0..255)
  float2 bsum;
  bsum.x = bc[m * Hn + c0] + br[m * Hn + c0] + enc_bias[c0];
  bsum.y = bc[m * Hn + c0 + 1] + br[m * Hn + c0 + 1] + enc_bias[c0 + 1];
#pragma unroll
  for (int i = 0; i < 8; i++) {
    int j = jo + i, e = lst[j];
    float hx = 0.f, hy = 0.f;
    if (e >= 0) {
      const float* lr = lut + (size_t)inp[e] * Hn;
      hx = tanhf(acc[i].x + bsum.x + lr[c0]);
      hy = tanhf(acc[i].y + bsum.y + lr[c0 + 1]);
    }
    xs2[(c0) * XSa + j] = hx;
    xs2[(c0 + 1) * XSa + j] = hy;
  }
  __syncthreads();  // xs2 visible block-wide (+ drains epilogue loads)

  // ================= phase B: comm_out slice + (ct==0) extras ==============
  const float* WoB = Wo + (size_t)m * Hn * On + ct * 256;
#pragma unroll
  for (int t = 0; t < 4; t++) issue_tile(WoB, On, t);

  if (ct == 0) {
    // hid global write, coalesced (512 thr = 2 examples per iter)
#pragma unroll 4
    for (int jj = 0; jj < 16; jj++) {
      int j = jj * 2 + (tid >> 8);
      int k = tid & 255;
      int e = lst[j];
      if (e >= 0) hid[(size_t)e * Hn + k] = xs2[k * XSa + j];
    }
    // softmax + baseline: wave w owns slots w*4 .. w*4+3 (shuffle-only)
    for (int s = 0; s < 4; s++) {
      int jt = w * 4 + s;
      int e = lst[jt];
      if (e < 0) continue;
      int l = lane, o = l & 15, kk = l >> 4;
      const float* wap = Wa + (size_t)m * Hn * NACTn + l;
      float al = 0.f;
      for (int w16 = 0; w16 < 4; w16++) {
        float wv[16], hv[16];
#pragma unroll
        for (int il = 0; il < 16; il++) wv[il] = wap[(w16 * 16 + il) * 64];
#pragma unroll
        for (int il = 0; il < 16; il++)
          hv[il] = xs2[(w16 * 64 + il * 4 + kk) * XSa + jt];
#pragma unroll
        for (int il = 0; il < 16; il++) al += wv[il] * hv[il];
      }
      al += __shfl_xor(al, 16);
      al += __shfl_xor(al, 32);
      al += ba[m * NACTn + o];

      float mx = al;
      mx = fmaxf(mx, __shfl_xor(mx, 1));
      mx = fmaxf(mx, __shfl_xor(mx, 2));
      mx = fmaxf(mx, __shfl_xor(mx, 4));
      mx = fmaxf(mx, __shfl_xor(mx, 8));
      float ex = expf(al - mx);
      float sm = ex;
      sm += __shfl_xor(sm, 1);
      sm += __shfl_xor(sm, 2);
      sm += __shfl_xor(sm, 4);
      sm += __shfl_xor(sm, 8);
      if (l < 16) aprob[e * NACTn + l] = ex / sm;

      float pb = 0.f;
      const float* wbp = Wb + (size_t)m * Hn;
      {
        float wv[4], hv[4];
#pragma unroll
        for (int k2 = 0; k2 < 4; k2++) {
          wv[k2] = wbp[l + k2 * 64];
          hv[k2] = xs2[(l + k2 * 64) * XSa + jt];
        }
#pragma unroll
        for (int k2 = 0; k2 < 4; k2++) pb += wv[k2] * hv[k2];
      }
      pb += __shfl_xor(pb, 1);
      pb += __shfl_xor(pb, 2);
      pb += __shfl_xor(pb, 4);
      pb += __shfl_xor(pb, 8);
      pb += __shfl_xor(pb, 16);
      pb += __shfl_xor(pb, 32);
      if (l == 0) bl[e] = pb + bb[m];
    }
  }

  float2 acc2[8];
#pragma unroll
  for (int i = 0; i < 8; i++) acc2[i] = make_float2(0.f, 0.f);
  stream16(WoB, On, xs2, acc2);  // k = hid col 0..255

  // epilogue B: bias + /7, write comm_out slice
  int cg = ct * 256 + c0;
  float2 bv = *(const float2*)(bo + (size_t)m * On + cg);
  const float inv = 1.f / 7.f;
#pragma unroll
  for (int i = 0; i < 8; i++) {
    int e = lst[jo + i];
    if (e < 0) continue;
    float2 o;
    o.x = (acc2[i].x + bv.x) * inv;
    o.y = (acc2[i].y + bv.y) * inv;
    *(float2*)(comm_out + (size_t)e * On + cg) = o;
  }
}

extern "C" void kernel_launch(void* const* d_in, const int* in_sizes, int n_in,
                              void* d_out, int out_size, void* d_ws, size_t ws_size,
                              hipStream_t stream) {
  const float* comm_in  = (const float*)d_in[0];
  const int*   inp      = (const int*)d_in[1];
  const float* prev_hid = (const float*)d_in[2];
  const int*   ids      = (const int*)d_in[4];
  const float* Wc = (const float*)d_in[5];
  const float* bc = (const float*)d_in[6];
  const float* Wr = (const float*)d_in[7];
  const float* br = (const float*)d_in[8];
  const float* Wa = (const float*)d_in[9];
  const float* ba = (const float*)d_in[10];
  const float* Wb = (const float*)d_in[11];
  const float* bb = (const float*)d_in[12];
  const float* Wo = (const float*)d_in[13];
  const float* bo = (const float*)d_in[14];
  const float* lut      = (const float*)d_in[15];
  const float* enc_bias = (const float*)d_in[16];

  float* out      = (float*)d_out;
  float* aprob    = out;                     // [512,16]
  float* bl       = out + Bn * NACTn;        // [512]
  float* hid      = out + Bn * NACTn + Bn;   // [512,256]
  float* comm_out = hid + Bn * Hn;           // [512,2048]

  (void)d_ws; (void)ws_size;  // workspace unused (R12+)

  // m-major grid: the 8 ct_o siblings of a model are 32 apart in linear id
  // -> same XCD (bid % 8 == m % 8) -> Wc/Wr L2-shared.
  k_fused<<<dim3(Mn, 8), 512, 0, stream>>>(
      Wc, Wr, Wo, comm_in, prev_hid, ids, inp, lut, enc_bias, bc, br, bo,
      Wa, ba, Wb, bb, hid, aprob, bl, comm_out);
}

// Round 9
// 166.837 us; speedup vs baseline: 1.3019x; 1.3019x over previous
//
#include <hip/hip_runtime.h>

// CommNet forward, fp32. B=512, M=32, H=256, NAG=8, NACT=16.
// R17: revert R16 fusion (1 blk/CU + 96 serialized barriers = 111us kernel;
// 2-blk/CU co-residency is mandatory for barrier-drain overlap — R7/R16).
// Back to R15 two-kernel structure (best, 170.7us). One change: k_outh inner
// loop re-blocked 4col x 4ex per lane -> 2 ds_reads (b128 W-quad + b128
// x-quad) per 16 FMA instead of 3 per 16; LDS issue is the k_outh floor
// (8 waves share 1 LDS pipe), so 48->32 reads/wave-tile cuts the dominant
// term ~33%. DMA/vmcnt/barrier skeleton byte-identical to R15. k_linh
// byte-identical to R15.
// Kept: deterministic ballot grouping (R14); DMA dest = wave-uniform base +
// lane*16B, 256-float chunks (R5); counted vmcnt never 0 in steady state
// (R11/R15); sched_barrier(0) pins (R13); 2 blk/CU (R7); no cooperative
// launch (R10); no acc8 (R12).

constexpr int Bn = 512, Mn = 32, NAGn = 8, Hn = 256, NACTn = 16;
constexpr int On = Hn * NAGn;  // 2048
constexpr int En = 32;         // padded slots/model (counts <= 32: held R1-R16)
constexpr int EW = 8;          // k_outh examples per wave
constexpr int XS = 40;         // k_outh x stride (16B-aligned float4 rows)
constexpr int XS3 = 20;        // k_linh x stride: 20*4=80B, %16==0 -> aligned b128

__device__ __forceinline__ void gl_lds16(const float* g, float* l) {
  __builtin_amdgcn_global_load_lds(
      (const __attribute__((address_space(1))) void*)g,
      (__attribute__((address_space(3))) void*)l, 16, 0, 0);
}

// Deterministic per-model example list: slot j = j-th example (by index e)
// with ids[e]==m. Identical in every block. Returns count. All 256 threads
// must call; two internal __syncthreads.
__device__ __forceinline__ int build_group_det(const int* __restrict__ ids,
                                               int m, int* lst, int* segc,
                                               int tid) {
  int w = tid >> 6, lane = tid & 63;
  if (tid < En) lst[tid] = -1;
  unsigned long long msk[2];
#pragma unroll
  for (int p = 0; p < 2; p++) {
    int i = (w * 2 + p) * 64 + lane;
    msk[p] = __ballot(ids[i] == m);
  }
  if (lane == 0) {
    segc[w * 2 + 0] = __popcll(msk[0]);
    segc[w * 2 + 1] = __popcll(msk[1]);
  }
  __syncthreads();
  int tot = 0;
#pragma unroll
  for (int q = 0; q < 8; q++) tot += segc[q];
#pragma unroll
  for (int p = 0; p < 2; p++) {
    int s = w * 2 + p;
    int pre = 0;
    for (int q = 0; q < 8; q++)
      if (q < s) pre += segc[q];
    int i = s * 64 + lane;
    if ((msk[p] >> lane) & 1ull) {
      int rank = pre + __popcll(msk[p] & ((1ull << lane) - 1ull));
      if (rank < En) lst[rank] = i;
    }
  }
  __syncthreads();
  return tot;
}

// -------- kernel 1: hid = tanh([comm-sum; prev_hid] @ [Wc; Wr] + biases) ----
// grid (32 m, 8 ct[32col], 2 jh[16ex]) = 512 blocks x 256 thr; 73.2 KB -> 2/CU.
__global__ __launch_bounds__(256) void k_linh(
    const float* __restrict__ Wc, const float* __restrict__ Wr,
    const float* __restrict__ comm_in, const float* __restrict__ prev_hid,
    const int* __restrict__ ids, const int* __restrict__ inp,
    const float* __restrict__ lut, const float* __restrict__ enc_bias,
    const float* __restrict__ bc, const float* __restrict__ br,
    float* __restrict__ hid) {
  int m = blockIdx.x, ct = blockIdx.y, jh = blockIdx.z;
  int tid = threadIdx.x, w = tid >> 6, lane = tid & 63;
  __shared__ int lst[En];
  __shared__ int segc[8];
  __shared__ alignas(16) float xs[512 * XS3];      // 40.96 KB: stacked K rows, 16 ex
  __shared__ alignas(16) float wbuf[2][128 * 32];  // 32 KB: 2-tile dbuf

  int cnt = build_group_det(ids, m, lst, segc, tid);
  if (cnt == 0) return;

  // DMA issue for stacked-W tile t (t0,t1 = Wc rows 0..127/128..255;
  // t2,t3 = Wr same). Tile = 16 chunks of 8 rows x 32 cols; 4 chunks/wave.
  // LDS layout resolves to row-major [128][32] (index 32*r + col).
  auto issue_tile = [&](int t, int buf) {
    const float* base = ((t < 2) ? Wc : Wr) + (size_t)m * Hn * Hn +
                        (size_t)((t & 1) * 128) * Hn + ct * 32;
    float* dst = wbuf[buf];
#pragma unroll
    for (int q = 0; q < 4; q++) {
      int c = w * 4 + q;
      int r = c * 8 + (lane >> 3);
      gl_lds16(base + (size_t)r * Hn + (lane & 7) * 4, dst + c * 256);
    }
  };
  issue_tile(0, 0);
  issue_tile(1, 1);

  // float4 staging of this block's 16 slots (local j 0..15 = global slot
  // jh*16 + j). tid -> kq = tid>>2 (16B K-quad), jg = tid&3; j = jg + 4*jj.
  // 36 float4 loads/thread, fully independent -> deep MLP; overlaps W DMA.
  {
    int kq = tid >> 2, jg = tid & 3;
#pragma unroll
    for (int jj = 0; jj < 4; jj++) {
      int j = jg + 4 * jj;
      int e = lst[jh * 16 + j];
      float4 vc = make_float4(0.f, 0.f, 0.f, 0.f);
      float4 vr = vc;
      if (e >= 0) {
        const float4* cp =
            (const float4*)(comm_in + (size_t)e * (NAGn * Hn)) + kq;
#pragma unroll
        for (int a = 0; a < NAGn; a++) {
          float4 t = cp[a * (Hn / 4)];
          vc.x += t.x; vc.y += t.y; vc.z += t.z; vc.w += t.w;
        }
        vr = *((const float4*)(prev_hid + (size_t)e * Hn) + kq);
      }
      int r = kq * 4;
      xs[(r + 0) * XS3 + j] = vc.x;
      xs[(r + 1) * XS3 + j] = vc.y;
      xs[(r + 2) * XS3 + j] = vc.z;
      xs[(r + 3) * XS3 + j] = vc.w;
      xs[(256 + r + 0) * XS3 + j] = vr.x;
      xs[(256 + r + 1) * XS3 + j] = vr.y;
      xs[(256 + r + 2) * XS3 + j] = vr.z;
      xs[(256 + r + 3) * XS3 + j] = vr.w;
    }
  }

  int j0 = w * 4;  // local slot base for this wave (4 slots/wave, 16/block)
  int kpar = lane >> 5, col = lane & 31;
  float acc[4];
#pragma unroll
  for (int i = 0; i < 4; i++) acc[i] = 0.f;

  // two dbuf rounds: {compute tiles 0,1} then {compute tiles 2,3}; each
  // round preceded by a full __syncthreads (vmcnt0+lgkm0 drain: all DMA
  // landed + xs visible). Safe at 2 blocks/CU (R7).
#pragma unroll
  for (int half = 0; half < 2; half++) {
    __syncthreads();
    __builtin_amdgcn_sched_barrier(0);  // pin: no LDS read hoists above
#pragma unroll
    for (int tt = 0; tt < 2; tt++) {
      int t = half * 2 + tt;
      const float* wb = wbuf[tt] + col;
      const float* xb = xs + (size_t)(t * 128 + kpar) * XS3 + j0;
#pragma unroll 8
      for (int kk = 0; kk < 64; kk++) {
        float wv = wb[(2 * kk + kpar) * 32];  // 2-way bank alias only (free)
        float4 xa = *(const float4*)(xb + (2 * kk) * XS3);
        acc[0] += xa.x * wv;
        acc[1] += xa.y * wv;
        acc[2] += xa.z * wv;
        acc[3] += xa.w * wv;
      }
    }
    if (half == 0) {
      // buffers fully consumed by THIS wave; re-issue for tiles 2,3. The
      // next __syncthreads orders all waves' reads before DMA lands.
      __builtin_amdgcn_sched_barrier(0);
      __syncthreads();  // all waves done reading wbuf before re-DMA
      issue_tile(2, 0);
      issue_tile(3, 1);
    }
  }

  // k-parity reduce (lanes l, l+32 hold even/odd-k partials of same col)
#pragma unroll
  for (int i = 0; i < 4; i++) acc[i] += __shfl_xor(acc[i], 32);
  if (lane < 32) {
    int cg = ct * 32 + lane;
    float bsum = bc[m * Hn + cg] + br[m * Hn + cg] + enc_bias[cg];
#pragma unroll
    for (int i = 0; i < 4; i++) {
      int e = lst[jh * 16 + j0 + i];
      if (e < 0) continue;
      float h = tanhf(acc[i] + bsum + lut[(size_t)inp[e] * Hn + cg]);
      hid[(size_t)e * Hn + cg] = h;
    }
  }
}

// -------- kernel 2: comm_out = (hid @ Wo + bo)/7; action/baseline ----------
// grid (16 ct[128col], 32 m) = 512 blocks x 256 thr; 72.9 KB LDS -> 2/CU.
// lst identical across blocks: block ct owns slots {ct, ct+16} (waves 0/1).
// R17: inner loop 4col x 4ex per lane: lane = g*32+c (c=col-quad 0..31,
// g=0..1); wave w owns ex-quads {2w, 2w+1} -> 2 b128 reads per 16 FMA.
__global__ __launch_bounds__(256) void k_outh(
    const float* __restrict__ Wo, const float* __restrict__ bo,
    const float* __restrict__ hid, const int* __restrict__ ids,
    const float* __restrict__ Wa, const float* __restrict__ ba,
    const float* __restrict__ Wb, const float* __restrict__ bb,
    float* __restrict__ aprob, float* __restrict__ bl,
    float* __restrict__ comm_out) {
  int ct = blockIdx.x, m = blockIdx.y;
  int tid = threadIdx.x, w = tid >> 6, lane = tid & 63;
  __shared__ int lst[En];
  __shared__ int segc[8];
  __shared__ alignas(16) float xs[Hn * XS];        // 40 KB
  __shared__ alignas(16) float wbuf[4][16 * 128];  // 32 KB: depth-3 stream

  int cnt = build_group_det(ids, m, lst, segc, tid);
  if (cnt == 0) return;

  // prologue: issue Wo tiles 0..3 (8 chunks/wave in flight); latency hides
  // under staging + softmax.
  const float* wsrc = Wo + (size_t)m * Hn * On + ct * 128;
  auto issue_tile = [&](int t) {
    const float* ws2 = wsrc + (size_t)t * 16 * On;
#pragma unroll
    for (int q = 0; q < 2; q++) {
      int c = w * 2 + q;
      int row = c * 2 + (lane >> 5);
      gl_lds16(ws2 + (size_t)row * On + (lane & 31) * 4,
               wbuf[t & 3] + c * 256);
    }
  };
#pragma unroll
  for (int t = 0; t < 4; t++) issue_tile(t);

  // stage x[k][j] from hid (manual transpose; tid = k). 32 coalesced loads.
  for (int j = 0; j < En; j++) {
    int e = lst[j];
    float v = (e >= 0) ? hid[(size_t)e * Hn + tid] : 0.f;
    xs[tid * XS + j] = v;
  }
  // staging barrier: lgkm only (do NOT drain the in-flight Wo DMA).
  asm volatile("s_waitcnt lgkmcnt(0)" ::: "memory");
  __builtin_amdgcn_s_barrier();
  __builtin_amdgcn_sched_barrier(0);  // pin: no xs read hoists above

  // action softmax + baseline for this block's slots: wave0 -> ct,
  // wave1 -> ct+16. Shuffle-only reductions; no block sync inside.
  {
    int jt = (w == 0) ? ct : (w == 1) ? ct + 16 : -1;
    int e = (jt >= 0) ? lst[jt] : -1;
    if (e >= 0) {
      int l = lane, o = l & 15, kk = l >> 4;
      const float* wap = Wa + (size_t)m * Hn * NACTn + l;
      float al = 0.f;
      for (int w16 = 0; w16 < 4; w16++) {
        float wv[16], hv[16];
#pragma unroll
        for (int il = 0; il < 16; il++) wv[il] = wap[(w16 * 16 + il) * 64];
#pragma unroll
        for (int il = 0; il < 16; il++)
          hv[il] = xs[(w16 * 64 + il * 4 + kk) * XS + jt];
#pragma unroll
        for (int il = 0; il < 16; il++) al += wv[il] * hv[il];
      }
      al += __shfl_xor(al, 16);
      al += __shfl_xor(al, 32);
      al += ba[m * NACTn + o];

      float mx = al;
      mx = fmaxf(mx, __shfl_xor(mx, 1));
      mx = fmaxf(mx, __shfl_xor(mx, 2));
      mx = fmaxf(mx, __shfl_xor(mx, 4));
      mx = fmaxf(mx, __shfl_xor(mx, 8));
      float ex = expf(al - mx);
      float sm = ex;
      sm += __shfl_xor(sm, 1);
      sm += __shfl_xor(sm, 2);
      sm += __shfl_xor(sm, 4);
      sm += __shfl_xor(sm, 8);
      if (l < 16) aprob[e * NACTn + l] = ex / sm;

      float pb = 0.f;
      const float* wbp = Wb + (size_t)m * Hn;
      {
        float wv[4], hv[4];
#pragma unroll
        for (int k2 = 0; k2 < 4; k2++) {
          wv[k2] = wbp[l + k2 * 64];
          hv[k2] = xs[(l + k2 * 64) * XS + jt];
        }
#pragma unroll
        for (int k2 = 0; k2 < 4; k2++) pb += wv[k2] * hv[k2];
      }
      pb += __shfl_xor(pb, 1);
      pb += __shfl_xor(pb, 2);
      pb += __shfl_xor(pb, 4);
      pb += __shfl_xor(pb, 8);
      pb += __shfl_xor(pb, 16);
      pb += __shfl_xor(pb, 32);
      if (l == 0) bl[e] = pb + bb[m];
    }
  }

  // Wo stream: 16 tiles x 16 rows; 4 buffers, depth-3, counted vmcnt.
  // Per-wave outstanding at top of iter t: tiles t..t+3 = 8 chunks (stores
  // from softmax are NEWER than the DMA -> in-order vmcnt keeps this safe).
  // 4c x 4e blocking: lane = g*32 + c; ex-quad q = w*2+g, cols c*4..c*4+3.
  int cq = (lane & 31) * 4;            // col base within 128
  int jq = (w * 2 + (lane >> 5)) * 4;  // ex slot base (8 quads = 32 slots)
  float4 acc[4];
#pragma unroll
  for (int i = 0; i < 4; i++) acc[i] = make_float4(0.f, 0.f, 0.f, 0.f);

  for (int t = 0; t < 16; t++) {
    if (t <= 12) {
      asm volatile("s_waitcnt vmcnt(6)" ::: "memory");
    } else if (t == 13) {
      asm volatile("s_waitcnt vmcnt(4)" ::: "memory");
    } else if (t == 14) {
      asm volatile("s_waitcnt vmcnt(2)" ::: "memory");
    } else {
      asm volatile("s_waitcnt vmcnt(0)" ::: "memory");
    }
    __builtin_amdgcn_s_barrier();       // all waves' tile-t chunks landed
    __builtin_amdgcn_sched_barrier(0);  // pin: no wbuf read hoists above
    const float* wb = wbuf[t & 3] + cq;
    const float* xb = xs + (size_t)(t * 16) * XS + jq;
#pragma unroll 8
    for (int k = 0; k < 16; k++) {
      float4 wv = *(const float4*)(wb + k * 128);
      float4 xv = *(const float4*)(xb + k * XS);
      acc[0].x += xv.x * wv.x; acc[0].y += xv.x * wv.y;
      acc[0].z += xv.x * wv.z; acc[0].w += xv.x * wv.w;
      acc[1].x += xv.y * wv.x; acc[1].y += xv.y * wv.y;
      acc[1].z += xv.y * wv.z; acc[1].w += xv.y * wv.w;
      acc[2].x += xv.z * wv.x; acc[2].y += xv.z * wv.y;
      acc[2].z += xv.z * wv.z; acc[2].w += xv.z * wv.w;
      acc[3].x += xv.w * wv.x; acc[3].y += xv.w * wv.y;
      acc[3].z += xv.w * wv.z; acc[3].w += xv.w * wv.w;
    }
    // trailing barrier releases wbuf[t&3]; re-issue for tile t+4 AFTER it
    // (all waves have finished reading) -> race-free, 3-iter issue-to-use.
    __builtin_amdgcn_sched_barrier(0);  // pin: no wbuf read sinks below
    __builtin_amdgcn_s_barrier();
    __builtin_amdgcn_sched_barrier(0);
    if (t <= 11) issue_tile(t + 4);
  }
  float4 bv = *(const float4*)(bo + (size_t)m * On + ct * 128 + cq);
  const float inv = 1.f / 7.f;
#pragma unroll
  for (int e4 = 0; e4 < 4; e4++) {
    int e = lst[jq + e4];
    if (e < 0) continue;
    float4 av = acc[e4];
    float4 o;
    o.x = (av.x + bv.x) * inv;
    o.y = (av.y + bv.y) * inv;
    o.z = (av.z + bv.z) * inv;
    o.w = (av.w + bv.w) * inv;
    *(float4*)(comm_out + (size_t)e * On + ct * 128 + cq) = o;
  }
}

extern "C" void kernel_launch(void* const* d_in, const int* in_sizes, int n_in,
                              void* d_out, int out_size, void* d_ws, size_t ws_size,
                              hipStream_t stream) {
  const float* comm_in  = (const float*)d_in[0];
  const int*   inp      = (const int*)d_in[1];
  const float* prev_hid = (const float*)d_in[2];
  const int*   ids      = (const int*)d_in[4];
  const float* Wc = (const float*)d_in[5];
  const float* bc = (const float*)d_in[6];
  const float* Wr = (const float*)d_in[7];
  const float* br = (const float*)d_in[8];
  const float* Wa = (const float*)d_in[9];
  const float* ba = (const float*)d_in[10];
  const float* Wb = (const float*)d_in[11];
  const float* bb = (const float*)d_in[12];
  const float* Wo = (const float*)d_in[13];
  const float* bo = (const float*)d_in[14];
  const float* lut      = (const float*)d_in[15];
  const float* enc_bias = (const float*)d_in[16];

  float* out      = (float*)d_out;
  float* aprob    = out;                     // [512,16]
  float* bl       = out + Bn * NACTn;        // [512]
  float* hid      = out + Bn * NACTn + Bn;   // [512,256]
  float* comm_out = hid + Bn * Hn;           // [512,2048]

  (void)d_ws; (void)ws_size;  // workspace unused (R12+)

  k_linh<<<dim3(Mn, 8, 2), 256, 0, stream>>>(Wc, Wr, comm_in, prev_hid, ids,
                                             inp, lut, enc_bias, bc, br, hid);
  k_outh<<<dim3(16, Mn), 256, 0, stream>>>(Wo, bo, hid, ids, Wa, ba, Wb, bb,
                                           aprob, bl, comm_out);
}

// Round 10
// 166.373 us; speedup vs baseline: 1.3056x; 1.0028x over previous
//
#include <hip/hip_runtime.h>

// CommNet forward, fp32. B=512, M=32, H=256, NAG=8, NACT=16.
// R18: k_linh compute re-block 2col x 4ex per lane, 4-way k-split
// (lane = kp(4) x c2(16)): per k-step 1 W-b64 + 1 x-b128 = 2 LDS reads per
// 8 FMA -> 64 reads/lane-tile vs R15's 128 (64 b32 + 64 b128). W b64 is
// 4-way-aliased across kp groups (1.58x, inherent: every kp group covers
// the full 32-word row); x is 4-addr broadcast (free). Epilogue: kp
// butterfly (shfl_xor 16,32) then lane (kp,c2) writes ex j0+kp cols
// cg..cg+1 (all 64 lanes, float2). Staging/DMA/strides/sync byte-identical
// to R15. k_outh byte-identical to R17 (4c x 4e; deeper re-block analyzed:
// k-split makes W reads 8-way-conflicted, net ~0).
// Kept: deterministic ballot grouping (R14); DMA dest = wave-uniform base +
// lane*16B, 256-float chunks (R5); counted vmcnt never 0 in steady state
// (R11/R15); sched_barrier(0) pins (R13); 2 blk/CU (R7/R16); no cooperative
// launch (R10); no acc8 (R12).

constexpr int Bn = 512, Mn = 32, NAGn = 8, Hn = 256, NACTn = 16;
constexpr int On = Hn * NAGn;  // 2048
constexpr int En = 32;         // padded slots/model (counts <= 32: held R1-R17)
constexpr int EW = 8;          // k_outh examples per wave
constexpr int XS = 40;         // k_outh x stride (16B-aligned float4 rows)
constexpr int XS3 = 20;        // k_linh x stride: 20*4=80B, %16==0 -> aligned b128

__device__ __forceinline__ void gl_lds16(const float* g, float* l) {
  __builtin_amdgcn_global_load_lds(
      (const __attribute__((address_space(1))) void*)g,
      (__attribute__((address_space(3))) void*)l, 16, 0, 0);
}

// Deterministic per-model example list: slot j = j-th example (by index e)
// with ids[e]==m. Identical in every block. Returns count. All 256 threads
// must call; two internal __syncthreads.
__device__ __forceinline__ int build_group_det(const int* __restrict__ ids,
                                               int m, int* lst, int* segc,
                                               int tid) {
  int w = tid >> 6, lane = tid & 63;
  if (tid < En) lst[tid] = -1;
  unsigned long long msk[2];
#pragma unroll
  for (int p = 0; p < 2; p++) {
    int i = (w * 2 + p) * 64 + lane;
    msk[p] = __ballot(ids[i] == m);
  }
  if (lane == 0) {
    segc[w * 2 + 0] = __popcll(msk[0]);
    segc[w * 2 + 1] = __popcll(msk[1]);
  }
  __syncthreads();
  int tot = 0;
#pragma unroll
  for (int q = 0; q < 8; q++) tot += segc[q];
#pragma unroll
  for (int p = 0; p < 2; p++) {
    int s = w * 2 + p;
    int pre = 0;
    for (int q = 0; q < 8; q++)
      if (q < s) pre += segc[q];
    int i = s * 64 + lane;
    if ((msk[p] >> lane) & 1ull) {
      int rank = pre + __popcll(msk[p] & ((1ull << lane) - 1ull));
      if (rank < En) lst[rank] = i;
    }
  }
  __syncthreads();
  return tot;
}

// -------- kernel 1: hid = tanh([comm-sum; prev_hid] @ [Wc; Wr] + biases) ----
// grid (32 m, 8 ct[32col], 2 jh[16ex]) = 512 blocks x 256 thr; 73.2 KB -> 2/CU.
__global__ __launch_bounds__(256) void k_linh(
    const float* __restrict__ Wc, const float* __restrict__ Wr,
    const float* __restrict__ comm_in, const float* __restrict__ prev_hid,
    const int* __restrict__ ids, const int* __restrict__ inp,
    const float* __restrict__ lut, const float* __restrict__ enc_bias,
    const float* __restrict__ bc, const float* __restrict__ br,
    float* __restrict__ hid) {
  int m = blockIdx.x, ct = blockIdx.y, jh = blockIdx.z;
  int tid = threadIdx.x, w = tid >> 6, lane = tid & 63;
  __shared__ int lst[En];
  __shared__ int segc[8];
  __shared__ alignas(16) float xs[512 * XS3];      // 40.96 KB: stacked K rows, 16 ex
  __shared__ alignas(16) float wbuf[2][128 * 32];  // 32 KB: 2-tile dbuf

  int cnt = build_group_det(ids, m, lst, segc, tid);
  if (cnt == 0) return;

  // DMA issue for stacked-W tile t (t0,t1 = Wc rows 0..127/128..255;
  // t2,t3 = Wr same). Tile = 16 chunks of 8 rows x 32 cols; 4 chunks/wave.
  // LDS layout resolves to row-major [128][32] (index 32*r + col).
  auto issue_tile = [&](int t, int buf) {
    const float* base = ((t < 2) ? Wc : Wr) + (size_t)m * Hn * Hn +
                        (size_t)((t & 1) * 128) * Hn + ct * 32;
    float* dst = wbuf[buf];
#pragma unroll
    for (int q = 0; q < 4; q++) {
      int c = w * 4 + q;
      int r = c * 8 + (lane >> 3);
      gl_lds16(base + (size_t)r * Hn + (lane & 7) * 4, dst + c * 256);
    }
  };
  issue_tile(0, 0);
  issue_tile(1, 1);

  // float4 staging of this block's 16 slots (local j 0..15 = global slot
  // jh*16 + j). tid -> kq = tid>>2 (16B K-quad), jg = tid&3; j = jg + 4*jj.
  // 36 float4 loads/thread, fully independent -> deep MLP; overlaps W DMA.
  {
    int kq = tid >> 2, jg = tid & 3;
#pragma unroll
    for (int jj = 0; jj < 4; jj++) {
      int j = jg + 4 * jj;
      int e = lst[jh * 16 + j];
      float4 vc = make_float4(0.f, 0.f, 0.f, 0.f);
      float4 vr = vc;
      if (e >= 0) {
        const float4* cp =
            (const float4*)(comm_in + (size_t)e * (NAGn * Hn)) + kq;
#pragma unroll
        for (int a = 0; a < NAGn; a++) {
          float4 t = cp[a * (Hn / 4)];
          vc.x += t.x; vc.y += t.y; vc.z += t.z; vc.w += t.w;
        }
        vr = *((const float4*)(prev_hid + (size_t)e * Hn) + kq);
      }
      int r = kq * 4;
      xs[(r + 0) * XS3 + j] = vc.x;
      xs[(r + 1) * XS3 + j] = vc.y;
      xs[(r + 2) * XS3 + j] = vc.z;
      xs[(r + 3) * XS3 + j] = vc.w;
      xs[(256 + r + 0) * XS3 + j] = vr.x;
      xs[(256 + r + 1) * XS3 + j] = vr.y;
      xs[(256 + r + 2) * XS3 + j] = vr.z;
      xs[(256 + r + 3) * XS3 + j] = vr.w;
    }
  }

  int j0 = w * 4;            // wave's 4 slots (16/block)
  int kp = lane >> 4;        // 0..3: k-residue (row = 4*kk + kp)
  int c2 = (lane & 15) * 2;  // col-pair base within 32
  float2 acc[4];             // acc[e] over this lane's 2 cols
#pragma unroll
  for (int i = 0; i < 4; i++) acc[i] = make_float2(0.f, 0.f);

  // two dbuf rounds: {compute tiles 0,1} then {compute tiles 2,3}; each
  // round preceded by a full __syncthreads (vmcnt0+lgkm0 drain: all DMA
  // landed + xs visible). Safe at 2 blocks/CU (R7).
#pragma unroll
  for (int half = 0; half < 2; half++) {
    __syncthreads();
    __builtin_amdgcn_sched_barrier(0);  // pin: no LDS read hoists above
#pragma unroll
    for (int tt = 0; tt < 2; tt++) {
      int t = half * 2 + tt;
      const float* wb = wbuf[tt] + c2;
      const float* xb = xs + (size_t)(t * 128 + kp) * XS3 + j0;
#pragma unroll 8
      for (int kk = 0; kk < 32; kk++) {
        float2 wv = *(const float2*)(wb + (4 * kk + kp) * 32);  // b64, 4-way
        float4 xa = *(const float4*)(xb + (4 * kk) * XS3);      // broadcast
        acc[0].x += xa.x * wv.x; acc[0].y += xa.x * wv.y;
        acc[1].x += xa.y * wv.x; acc[1].y += xa.y * wv.y;
        acc[2].x += xa.z * wv.x; acc[2].y += xa.z * wv.y;
        acc[3].x += xa.w * wv.x; acc[3].y += xa.w * wv.y;
      }
    }
    if (half == 0) {
      // buffers fully consumed by THIS wave; re-issue for tiles 2,3. The
      // next __syncthreads orders all waves' reads before DMA lands.
      __builtin_amdgcn_sched_barrier(0);
      __syncthreads();  // all waves done reading wbuf before re-DMA
      issue_tile(2, 0);
      issue_tile(3, 1);
    }
  }

  // kp butterfly (lane bits 4,5): every lane ends with full-k totals
#pragma unroll
  for (int i = 0; i < 4; i++) {
    acc[i].x += __shfl_xor(acc[i].x, 16);
    acc[i].y += __shfl_xor(acc[i].y, 16);
    acc[i].x += __shfl_xor(acc[i].x, 32);
    acc[i].y += __shfl_xor(acc[i].y, 32);
  }
  // epilogue: lane (kp, c2) owns ex j0+kp, cols cg..cg+1 (all 64 lanes)
  {
    int e = lst[jh * 16 + j0 + kp];
    if (e >= 0) {
      int cg = ct * 32 + c2;
      float2 bcv = *(const float2*)(bc + (size_t)m * Hn + cg);
      float2 brv = *(const float2*)(br + (size_t)m * Hn + cg);
      float2 ebv = *(const float2*)(enc_bias + cg);
      const float* lr = lut + (size_t)inp[e] * Hn + cg;
      float2 h;
      h.x = tanhf(acc[kp].x + bcv.x + brv.x + ebv.x + lr[0]);
      h.y = tanhf(acc[kp].y + bcv.y + brv.y + ebv.y + lr[1]);
      *(float2*)(hid + (size_t)e * Hn + cg) = h;
    }
  }
}

// -------- kernel 2: comm_out = (hid @ Wo + bo)/7; action/baseline ----------
// grid (16 ct[128col], 32 m) = 512 blocks x 256 thr; 72.9 KB LDS -> 2/CU.
// lst identical across blocks: block ct owns slots {ct, ct+16} (waves 0/1).
// 4c x 4e per lane (R17): lane = g*32+c; wave w owns ex-quads {2w, 2w+1}.
__global__ __launch_bounds__(256) void k_outh(
    const float* __restrict__ Wo, const float* __restrict__ bo,
    const float* __restrict__ hid, const int* __restrict__ ids,
    const float* __restrict__ Wa, const float* __restrict__ ba,
    const float* __restrict__ Wb, const float* __restrict__ bb,
    float* __restrict__ aprob, float* __restrict__ bl,
    float* __restrict__ comm_out) {
  int ct = blockIdx.x, m = blockIdx.y;
  int tid = threadIdx.x, w = tid >> 6, lane = tid & 63;
  __shared__ int lst[En];
  __shared__ int segc[8];
  __shared__ alignas(16) float xs[Hn * XS];        // 40 KB
  __shared__ alignas(16) float wbuf[4][16 * 128];  // 32 KB: depth-3 stream

  int cnt = build_group_det(ids, m, lst, segc, tid);
  if (cnt == 0) return;

  // prologue: issue Wo tiles 0..3 (8 chunks/wave in flight); latency hides
  // under staging + softmax.
  const float* wsrc = Wo + (size_t)m * Hn * On + ct * 128;
  auto issue_tile = [&](int t) {
    const float* ws2 = wsrc + (size_t)t * 16 * On;
#pragma unroll
    for (int q = 0; q < 2; q++) {
      int c = w * 2 + q;
      int row = c * 2 + (lane >> 5);
      gl_lds16(ws2 + (size_t)row * On + (lane & 31) * 4,
               wbuf[t & 3] + c * 256);
    }
  };
#pragma unroll
  for (int t = 0; t < 4; t++) issue_tile(t);

  // stage x[k][j] from hid (manual transpose; tid = k). 32 coalesced loads.
  for (int j = 0; j < En; j++) {
    int e = lst[j];
    float v = (e >= 0) ? hid[(size_t)e * Hn + tid] : 0.f;
    xs[tid * XS + j] = v;
  }
  // staging barrier: lgkm only (do NOT drain the in-flight Wo DMA).
  asm volatile("s_waitcnt lgkmcnt(0)" ::: "memory");
  __builtin_amdgcn_s_barrier();
  __builtin_amdgcn_sched_barrier(0);  // pin: no xs read hoists above

  // action softmax + baseline for this block's slots: wave0 -> ct,
  // wave1 -> ct+16. Shuffle-only reductions; no block sync inside.
  {
    int jt = (w == 0) ? ct : (w == 1) ? ct + 16 : -1;
    int e = (jt >= 0) ? lst[jt] : -1;
    if (e >= 0) {
      int l = lane, o = l & 15, kk = l >> 4;
      const float* wap = Wa + (size_t)m * Hn * NACTn + l;
      float al = 0.f;
      for (int w16 = 0; w16 < 4; w16++) {
        float wv[16], hv[16];
#pragma unroll
        for (int il = 0; il < 16; il++) wv[il] = wap[(w16 * 16 + il) * 64];
#pragma unroll
        for (int il = 0; il < 16; il++)
          hv[il] = xs[(w16 * 64 + il * 4 + kk) * XS + jt];
#pragma unroll
        for (int il = 0; il < 16; il++) al += wv[il] * hv[il];
      }
      al += __shfl_xor(al, 16);
      al += __shfl_xor(al, 32);
      al += ba[m * NACTn + o];

      float mx = al;
      mx = fmaxf(mx, __shfl_xor(mx, 1));
      mx = fmaxf(mx, __shfl_xor(mx, 2));
      mx = fmaxf(mx, __shfl_xor(mx, 4));
      mx = fmaxf(mx, __shfl_xor(mx, 8));
      float ex = expf(al - mx);
      float sm = ex;
      sm += __shfl_xor(sm, 1);
      sm += __shfl_xor(sm, 2);
      sm += __shfl_xor(sm, 4);
      sm += __shfl_xor(sm, 8);
      if (l < 16) aprob[e * NACTn + l] = ex / sm;

      float pb = 0.f;
      const float* wbp = Wb + (size_t)m * Hn;
      {
        float wv[4], hv[4];
#pragma unroll
        for (int k2 = 0; k2 < 4; k2++) {
          wv[k2] = wbp[l + k2 * 64];
          hv[k2] = xs[(l + k2 * 64) * XS + jt];
        }
#pragma unroll
        for (int k2 = 0; k2 < 4; k2++) pb += wv[k2] * hv[k2];
      }
      pb += __shfl_xor(pb, 1);
      pb += __shfl_xor(pb, 2);
      pb += __shfl_xor(pb, 4);
      pb += __shfl_xor(pb, 8);
      pb += __shfl_xor(pb, 16);
      pb += __shfl_xor(pb, 32);
      if (l == 0) bl[e] = pb + bb[m];
    }
  }

  // Wo stream: 16 tiles x 16 rows; 4 buffers, depth-3, counted vmcnt.
  // Per-wave outstanding at top of iter t: tiles t..t+3 = 8 chunks (stores
  // from softmax are NEWER than the DMA -> in-order vmcnt keeps this safe).
  // 4c x 4e blocking: lane = g*32 + c; ex-quad q = w*2+g, cols c*4..c*4+3.
  int cq = (lane & 31) * 4;            // col base within 128
  int jq = (w * 2 + (lane >> 5)) * 4;  // ex slot base (8 quads = 32 slots)
  float4 acc[4];
#pragma unroll
  for (int i = 0; i < 4; i++) acc[i] = make_float4(0.f, 0.f, 0.f, 0.f);

  for (int t = 0; t < 16; t++) {
    if (t <= 12) {
      asm volatile("s_waitcnt vmcnt(6)" ::: "memory");
    } else if (t == 13) {
      asm volatile("s_waitcnt vmcnt(4)" ::: "memory");
    } else if (t == 14) {
      asm volatile("s_waitcnt vmcnt(2)" ::: "memory");
    } else {
      asm volatile("s_waitcnt vmcnt(0)" ::: "memory");
    }
    __builtin_amdgcn_s_barrier();       // all waves' tile-t chunks landed
    __builtin_amdgcn_sched_barrier(0);  // pin: no wbuf read hoists above
    const float* wb = wbuf[t & 3] + cq;
    const float* xb = xs + (size_t)(t * 16) * XS + jq;
#pragma unroll 8
    for (int k = 0; k < 16; k++) {
      float4 wv = *(const float4*)(wb + k * 128);
      float4 xv = *(const float4*)(xb + k * XS);
      acc[0].x += xv.x * wv.x; acc[0].y += xv.x * wv.y;
      acc[0].z += xv.x * wv.z; acc[0].w += xv.x * wv.w;
      acc[1].x += xv.y * wv.x; acc[1].y += xv.y * wv.y;
      acc[1].z += xv.y * wv.z; acc[1].w += xv.y * wv.w;
      acc[2].x += xv.z * wv.x; acc[2].y += xv.z * wv.y;
      acc[2].z += xv.z * wv.z; acc[2].w += xv.z * wv.w;
      acc[3].x += xv.w * wv.x; acc[3].y += xv.w * wv.y;
      acc[3].z += xv.w * wv.z; acc[3].w += xv.w * wv.w;
    }
    // trailing barrier releases wbuf[t&3]; re-issue for tile t+4 AFTER it
    // (all waves have finished reading) -> race-free, 3-iter issue-to-use.
    __builtin_amdgcn_sched_barrier(0);  // pin: no wbuf read sinks below
    __builtin_amdgcn_s_barrier();
    __builtin_amdgcn_sched_barrier(0);
    if (t <= 11) issue_tile(t + 4);
  }
  float4 bv = *(const float4*)(bo + (size_t)m * On + ct * 128 + cq);
  const float inv = 1.f / 7.f;
#pragma unroll
  for (int e4 = 0; e4 < 4; e4++) {
    int e = lst[jq + e4];
    if (e < 0) continue;
    float4 av = acc[e4];
    float4 o;
    o.x = (av.x + bv.x) * inv;
    o.y = (av.y + bv.y) * inv;
    o.z = (av.z + bv.z) * inv;
    o.w = (av.w + bv.w) * inv;
    *(float4*)(comm_out + (size_t)e * On + ct * 128 + cq) = o;
  }
}

extern "C" void kernel_launch(void* const* d_in, const int* in_sizes, int n_in,
                              void* d_out, int out_size, void* d_ws, size_t ws_size,
                              hipStream_t stream) {
  const float* comm_in  = (const float*)d_in[0];
  const int*   inp      = (const int*)d_in[1];
  const float* prev_hid = (const float*)d_in[2];
  const int*   ids      = (const int*)d_in[4];
  const float* Wc = (const float*)d_in[5];
  const float* bc = (const float*)d_in[6];
  const float* Wr = (const float*)d_in[7];
  const float* br = (const float*)d_in[8];
  const float* Wa = (const float*)d_in[9];
  const float* ba = (const float*)d_in[10];
  const float* Wb = (const float*)d_in[11];
  const float* bb = (const float*)d_in[12];
  const float* Wo = (const float*)d_in[13];
  const float* bo = (const float*)d_in[14];
  const float* lut      = (const float*)d_in[15];
  const float* enc_bias = (const float*)d_in[16];

  float* out      = (float*)d_out;
  float* aprob    = out;                     // [512,16]
  float* bl       = out + Bn * NACTn;        // [512]
  float* hid      = out + Bn * NACTn + Bn;   // [512,256]
  float* comm_out = hid + Bn * Hn;           // [512,2048]

  (void)d_ws; (void)ws_size;  // workspace unused (R12+)

  k_linh<<<dim3(Mn, 8, 2), 256, 0, stream>>>(Wc, Wr, comm_in, prev_hid, ids,
                                             inp, lut, enc_bias, bc, br, hid);
  k_outh<<<dim3(16, Mn), 256, 0, stream>>>(Wo, bo, hid, ids, Wa, ba, Wb, bb,
                                           aprob, bl, comm_out);
}